// Round 13
// baseline (1439.146 us; speedup 1.0000x reference)
//
#include <hip/hip_runtime.h>
#include <hip/hip_fp16.h>

#define N_NODES 50000
#define N_HID   64
#define N_LAYER 4
#define N_CLASS 40
#define N_EDGES 800000

#define BSHIFT 8
#define BSIZE  256                                      // nodes per bucket
#define NBUCK  ((N_NODES + BSIZE - 1) / BSIZE)          // 196
#define BPAD   16                                      // bucket-cursor stride (64B)
#define EPT    16                                      // edges per thread (bucket pass)
#define BKCHUNK (256 * EPT)                             // 4096 edges per block
#define NBBLK  ((N_EDGES + BKCHUNK - 1) / BKCHUNK)      // 196

#define SCAP  5120                                      // fixed stag window per bucket
#define PBK   (SCAP + 7 * BSIZE)                        // 6912: padded CSR window
#define DUMMY N_NODES                                   // index of zeroed hd row
#define NGRP  (N_NODES / 16)                            // 3125 16-node groups

// ---------------- init: bucket cursors + dummy hd rows ----------------

__global__ void k_zerob(int* __restrict__ bcur, __half* __restrict__ hdA,
                        __half* __restrict__ hdB) {
    int t = threadIdx.x;
    if (t < NBUCK) bcur[t * BPAD] = t * SCAP;
    if (t < 64) {
        hdA[(size_t)N_NODES * 64 + t] = __float2half(0.f);
        hdB[(size_t)N_NODES * 64 + t] = __float2half(0.f);
    }
}

// ---------------- block-binned append of packed (dst<<16)|src into fixed bucket windows ----------------

__global__ void k_bucket(const int* __restrict__ src, const int* __restrict__ dst,
                         int* __restrict__ bcur, unsigned int* __restrict__ stag) {
    __shared__ int lhist[NBUCK];
    __shared__ int gbase[NBUCK];
    int t = threadIdx.x;
    for (int i = t; i < NBUCK; i += 256) lhist[i] = 0;
    __syncthreads();

    int base = blockIdx.x * BKCHUNK;
    unsigned int rec[EPT];
    int br[EPT];
#pragma unroll
    for (int i = 0; i < EPT; i++) {
        int e = base + i * 256 + t;      // coalesced
        if (e < N_EDGES) {
            int d = dst[e], s = src[e];
            int b = d >> BSHIFT;
            int r = atomicAdd(&lhist[b], 1);   // in-block rank within bucket
            rec[i] = ((unsigned int)d << 16) | (unsigned int)s;
            br[i]  = (b << 16) | r;            // r < 4096
        } else {
            br[i] = -1;
        }
    }
    __syncthreads();
    for (int i = t; i < NBUCK; i += 256) {
        int c = lhist[i];
        gbase[i] = c ? atomicAdd(&bcur[i * BPAD], c) : 0;
    }
    __syncthreads();
#pragma unroll
    for (int i = 0; i < EPT; i++) {
        if (br[i] >= 0) {
            int b = br[i] >> 16, r = br[i] & 0xffff;
            stag[gbase[b] + r] = rec[i];
        }
    }
}

// ---------------- per-bucket: count + scan -> padded CSR of (dloc<<16)|src ----------------
// Rows padded to multiples of 8 with DUMMY; per-16-node-group slot ranges in gs/ge.

__global__ void k_csr2(const unsigned int* __restrict__ stag, const int* __restrict__ bcur,
                       float* __restrict__ dinv, int* __restrict__ gs, int* __restrict__ ge,
                       unsigned int* __restrict__ ecsr) {
    __shared__ int lcnt[BSIZE], ltmp[BSIZE], lcur[BSIZE];
    int b = blockIdx.x, t = threadIdx.x;
    int bstart = b * SCAP;
    int bend   = bcur[b * BPAD];         // post-append cursor = bucket end
    lcnt[t] = 0;
    __syncthreads();
    for (int i = bstart + t; i < bend; i += 256)
        atomicAdd(&lcnt[(stag[i] >> 16) & (BSIZE - 1)], 1);
    __syncthreads();
    int v = lcnt[t];
    int p = (v + 7) & ~7;                // padded row size
    ltmp[t] = p;
    __syncthreads();
    for (int off = 1; off < 256; off <<= 1) {
        int u = (t >= off) ? ltmp[t - off] : 0;
        __syncthreads();
        ltmp[t] += u;
        __syncthreads();
    }
    int pstart = b * PBK + ltmp[t] - p;  // node's padded CSR row start
    lcur[t] = pstart;
    int node = (b << BSHIFT) + t;
    if (node < N_NODES) {
        dinv[node] = rsqrtf((float)(v + 1));
        int g = node >> 4;               // 16-node group id (groups align w/ buckets)
        if ((t & 15) == 0)  gs[g] = pstart;
        if ((t & 15) == 15) ge[g] = pstart + p;
    }
    __syncthreads();
    for (int i = bstart + t; i < bend; i += 256) {
        unsigned int rec = stag[i];
        int d = (rec >> 16) & (BSIZE - 1);
        int pos = atomicAdd(&lcur[d], 1);
        ecsr[pos] = (((rec >> 16) & 15u) << 16) | (rec & 0xffffu);   // dloc = dst & 15
    }
    for (int i = v; i < p; i++)          // pad with dummy zero-row
        ecsr[pstart + i] = (((unsigned int)(t & 15)) << 16) | (unsigned int)DUMMY;
}

// ---------------- layer-0 GEMM (tiled, 4 acc/thread): hd = half((x@W0)*dinv) ----------------

__global__ __launch_bounds__(256) void k_gemm0(const float* __restrict__ A,
                                               const float* __restrict__ W,
                                               const float* __restrict__ dinv,
                                               __half* __restrict__ hd) {
    __shared__ float As[16][128];
    int tid = threadIdx.x;
    int j  = tid & 63;
    int nl = tid >> 6;              // 0..3
    int node0 = blockIdx.x * 16;

    const float4* srcp = (const float4*)(A + (size_t)node0 * 128);
    float4* dstp = (float4*)&As[0][0];
    for (int idx = tid; idx < 16 * 128 / 4; idx += 256) dstp[idx] = srcp[idx];
    __syncthreads();

    float acc[4] = {0.f, 0.f, 0.f, 0.f};
#pragma unroll
    for (int k = 0; k < 128; k += 4) {
        float4 a0 = *(const float4*)&As[nl * 4 + 0][k];   // wave-uniform broadcast
        float4 a1 = *(const float4*)&As[nl * 4 + 1][k];
        float4 a2 = *(const float4*)&As[nl * 4 + 2][k];
        float4 a3 = *(const float4*)&As[nl * 4 + 3][k];
        float w0 = W[(k + 0) * 64 + j];
        float w1 = W[(k + 1) * 64 + j];
        float w2 = W[(k + 2) * 64 + j];
        float w3 = W[(k + 3) * 64 + j];
        acc[0] = fmaf(a0.w, w3, fmaf(a0.z, w2, fmaf(a0.y, w1, fmaf(a0.x, w0, acc[0]))));
        acc[1] = fmaf(a1.w, w3, fmaf(a1.z, w2, fmaf(a1.y, w1, fmaf(a1.x, w0, acc[1]))));
        acc[2] = fmaf(a2.w, w3, fmaf(a2.z, w2, fmaf(a2.y, w1, fmaf(a2.x, w0, acc[2]))));
        acc[3] = fmaf(a3.w, w3, fmaf(a3.z, w2, fmaf(a3.y, w1, fmaf(a3.x, w0, acc[3]))));
    }
#pragma unroll
    for (int i = 0; i < 4; i++) {
        int n = node0 + nl * 4 + i;
        hd[(size_t)n * 64 + j] = __float2half(acc[i] * dinv[n]);
    }
}

// ---------------- edge-parallel agg into LDS acc (device fn) ----------------
// 16 sub-waves x 16 lanes; per edge: 16 lanes read the 128B row, ds_add into acc[dloc].

__device__ __forceinline__ void agg_block(const __half2* __restrict__ hd_in,
                                          const unsigned int* __restrict__ ecsr,
                                          int ebase, int eend, int tid,
                                          float (*acc)[64]) {
    int swid = tid >> 4;          // sub-wave 0..15
    int j16  = tid & 15;          // feature quad
    for (int e = ebase + swid; e < eend; e += 16) {
        unsigned int rec = ecsr[e];            // broadcast read (same addr in sub-wave)
        int dloc = rec >> 16;
        int srcn = rec & 0xffff;
        const __half2* row = hd_in + (size_t)srcn * 32 + j16 * 2;
        float2 v0 = __half22float2(row[0]);    // 8B per lane, 128B per edge
        float2 v1 = __half22float2(row[1]);
        atomicAdd(&acc[dloc][j16 * 4 + 0], v0.x);
        atomicAdd(&acc[dloc][j16 * 4 + 1], v0.y);
        atomicAdd(&acc[dloc][j16 * 4 + 2], v1.x);
        atomicAdd(&acc[dloc][j16 * 4 + 3], v1.y);
    }
}

// finalize: acc = relu((acc + self)*dinv + b); each thread owns node tid>>4, feats (tid&15)*4..+3
__device__ __forceinline__ void finalize_block(const __half2* __restrict__ hd_in,
                                               const float* __restrict__ b,
                                               const float* __restrict__ dinv,
                                               int node0, int tid,
                                               float (*acc)[64], __half* __restrict__ hs_out) {
    int nl = tid >> 4, f0 = (tid & 15) * 4;
    int n = node0 + nl;
    float dv = dinv[n];
    float2 s0 = __half22float2(hd_in[(size_t)n * 32 + (f0 >> 1)]);
    float2 s1 = __half22float2(hd_in[(size_t)n * 32 + (f0 >> 1) + 1]);
    float o0 = fmaxf(fmaf(acc[nl][f0 + 0] + s0.x, dv, b[f0 + 0]), 0.f);
    float o1 = fmaxf(fmaf(acc[nl][f0 + 1] + s0.y, dv, b[f0 + 1]), 0.f);
    float o2 = fmaxf(fmaf(acc[nl][f0 + 2] + s1.x, dv, b[f0 + 2]), 0.f);
    float o3 = fmaxf(fmaf(acc[nl][f0 + 3] + s1.y, dv, b[f0 + 3]), 0.f);
    acc[nl][f0 + 0] = o0; acc[nl][f0 + 1] = o1;
    acc[nl][f0 + 2] = o2; acc[nl][f0 + 3] = o3;
    if (hs_out) {
        ((__half2*)hs_out)[(size_t)n * 32 + (f0 >> 1)] =
            __halves2half2(__float2half(o0), __float2half(o1));
        ((__half2*)hs_out)[(size_t)n * 32 + (f0 >> 1) + 1] =
            __halves2half2(__float2half(o2), __float2half(o3));
    }
}

// ---------------- layer: edge-parallel agg + finalize + full-block tiled gemm ----------------

__global__ __launch_bounds__(256) void k_layer(const __half2* __restrict__ hd_in,
                                               const float* __restrict__ b,
                                               const float* __restrict__ dinv,
                                               const int* __restrict__ gs,
                                               const int* __restrict__ ge,
                                               const unsigned int* __restrict__ ecsr,
                                               const float* __restrict__ W,
                                               __half* __restrict__ hs_out,
                                               __half* __restrict__ hd_out) {
    __shared__ float acc[16][64];
    int tid = threadIdx.x;
    int node0 = blockIdx.x * 16;

    ((float4*)&acc[0][0])[tid] = make_float4(0.f, 0.f, 0.f, 0.f);
    __syncthreads();

    agg_block(hd_in, ecsr, gs[blockIdx.x], ge[blockIdx.x], tid, acc);
    __syncthreads();

    finalize_block(hd_in, b, dinv, node0, tid, acc, hs_out);
    __syncthreads();

    // tiled gemm: 16 nodes x 64 cols, 4 nodes/thread, all 4 waves active
    int j  = tid & 63;
    int nl = tid >> 6;
    float r[4] = {0.f, 0.f, 0.f, 0.f};
#pragma unroll
    for (int k = 0; k < 64; k += 4) {
        float4 a0 = *(const float4*)&acc[nl * 4 + 0][k];
        float4 a1 = *(const float4*)&acc[nl * 4 + 1][k];
        float4 a2 = *(const float4*)&acc[nl * 4 + 2][k];
        float4 a3 = *(const float4*)&acc[nl * 4 + 3][k];
        float w0 = W[(k + 0) * 64 + j];
        float w1 = W[(k + 1) * 64 + j];
        float w2 = W[(k + 2) * 64 + j];
        float w3 = W[(k + 3) * 64 + j];
        r[0] = fmaf(a0.w, w3, fmaf(a0.z, w2, fmaf(a0.y, w1, fmaf(a0.x, w0, r[0]))));
        r[1] = fmaf(a1.w, w3, fmaf(a1.z, w2, fmaf(a1.y, w1, fmaf(a1.x, w0, r[1]))));
        r[2] = fmaf(a2.w, w3, fmaf(a2.z, w2, fmaf(a2.y, w1, fmaf(a2.x, w0, r[2]))));
        r[3] = fmaf(a3.w, w3, fmaf(a3.z, w2, fmaf(a3.y, w1, fmaf(a3.x, w0, r[3]))));
    }
#pragma unroll
    for (int i = 0; i < 4; i++) {
        int n = node0 + nl * 4 + i;
        hd_out[(size_t)n * 64 + j] = __float2half(r[i] * dinv[n]);
    }
}

// ---------------- last: agg + finalize + attention + projection ----------------

__global__ __launch_bounds__(256) void k_last(const __half2* __restrict__ hd_in,
                                              const float* __restrict__ b,
                                              const float* __restrict__ dinv,
                                              const int* __restrict__ gs,
                                              const int* __restrict__ ge,
                                              const unsigned int* __restrict__ ecsr,
                                              const __half* __restrict__ hs16,
                                              const float* __restrict__ Wout,
                                              const float* __restrict__ bout,
                                              float* __restrict__ out) {
    __shared__ float acc[16][64];
    __shared__ float bl[16][64];
    int tid = threadIdx.x;
    int node0 = blockIdx.x * 16;

    ((float4*)&acc[0][0])[tid] = make_float4(0.f, 0.f, 0.f, 0.f);
    __syncthreads();

    agg_block(hd_in, ecsr, gs[blockIdx.x], ge[blockIdx.x], tid, acc);
    __syncthreads();

    finalize_block(hd_in, b, dinv, node0, tid, acc, nullptr);
    __syncthreads();

    // attention: wave w handles nodes w*4..w*4+3, 64 lanes per node
    int lane = tid & 63, w = tid >> 6;
    for (int i = 0; i < 4; i++) {
        int nloc = w * 4 + i;
        int n = node0 + nloc;
        float v[N_LAYER], sc[N_LAYER];
#pragma unroll
        for (int l = 0; l < 3; l++) {
            float val = __half2float(hs16[((size_t)l * N_NODES + n) * 64 + lane]);
            v[l]  = val;
            sc[l] = val * val;
        }
        v[3]  = acc[nloc][lane];
        sc[3] = v[3] * v[3];
#pragma unroll
        for (int off = 32; off > 0; off >>= 1) {
#pragma unroll
            for (int l = 0; l < N_LAYER; l++) sc[l] += __shfl_xor(sc[l], off, 64);
        }
        float m = fmaxf(fmaxf(sc[0], sc[1]), fmaxf(sc[2], sc[3]));
        float e[N_LAYER];
        float sum = 0.f;
#pragma unroll
        for (int l = 0; l < N_LAYER; l++) { e[l] = __expf(sc[l] - m); sum += e[l]; }
        float inv = 1.f / sum;
        float blv = 0.f;
#pragma unroll
        for (int l = 0; l < N_LAYER; l++) blv = fmaf(e[l] * inv, v[l], blv);
        bl[nloc][lane] = blv;
    }
    __syncthreads();

    // projection: wave w covers its 4 nodes, 4 acc/thread, lanes 0..39
    if (lane < N_CLASS) {
        float r[4] = {bout[lane], bout[lane], bout[lane], bout[lane]};
#pragma unroll
        for (int k = 0; k < 64; k += 4) {
            float4 a0 = *(const float4*)&bl[w * 4 + 0][k];
            float4 a1 = *(const float4*)&bl[w * 4 + 1][k];
            float4 a2 = *(const float4*)&bl[w * 4 + 2][k];
            float4 a3 = *(const float4*)&bl[w * 4 + 3][k];
            float w0 = Wout[(k + 0) * N_CLASS + lane];
            float w1 = Wout[(k + 1) * N_CLASS + lane];
            float w2 = Wout[(k + 2) * N_CLASS + lane];
            float w3 = Wout[(k + 3) * N_CLASS + lane];
            r[0] = fmaf(a0.w, w3, fmaf(a0.z, w2, fmaf(a0.y, w1, fmaf(a0.x, w0, r[0]))));
            r[1] = fmaf(a1.w, w3, fmaf(a1.z, w2, fmaf(a1.y, w1, fmaf(a1.x, w0, r[1]))));
            r[2] = fmaf(a2.w, w3, fmaf(a2.z, w2, fmaf(a2.y, w1, fmaf(a2.x, w0, r[2]))));
            r[3] = fmaf(a3.w, w3, fmaf(a3.z, w2, fmaf(a3.y, w1, fmaf(a3.x, w0, r[3]))));
        }
#pragma unroll
        for (int i = 0; i < 4; i++)
            out[(size_t)(node0 + w * 4 + i) * N_CLASS + lane] = r[i];
    }
}

// ---------------- launch ----------------

extern "C" void kernel_launch(void* const* d_in, const int* in_sizes, int n_in,
                              void* d_out, int out_size, void* d_ws, size_t ws_size,
                              hipStream_t stream) {
    const float* x    = (const float*)d_in[0];
    const float* W0   = (const float*)d_in[1];
    const float* b0   = (const float*)d_in[2];
    const float* Ws   = (const float*)d_in[3];
    const float* bs   = (const float*)d_in[4];
    const float* Wout = (const float*)d_in[5];
    const float* bout = (const float*)d_in[6];
    const int*   ei   = (const int*)d_in[7];
    const int* src = ei;
    const int* dst = ei + N_EDGES;
    float* out = (float*)d_out;

    int*            bcur  = (int*)d_ws;                             // NBUCK*BPAD
    float*          dinv  = (float*)(bcur + NBUCK * BPAD);          // N
    int*            gs    = (int*)(dinv + N_NODES);                 // NGRP
    int*            ge    = gs + NGRP;                              // NGRP
    unsigned int*   ecsr  = (unsigned int*)(ge + NGRP);             // NBUCK*PBK
    __half*         hdA   = (__half*)(ecsr + (size_t)NBUCK * PBK);  // (N+1)*64
    __half*         hdB   = hdA + (size_t)(N_NODES + 1) * 64;       // (N+1)*64
    __half*         hs16  = hdB + (size_t)(N_NODES + 1) * 64;       // 3*N*64
    unsigned int*   stag  = (unsigned int*)hs16;                    // NBUCK*SCAP, aliased (build only)

    k_zerob <<<1, 256, 0, stream>>>(bcur, hdA, hdB);
    k_bucket<<<NBBLK, 256, 0, stream>>>(src, dst, bcur, stag);
    k_csr2  <<<NBUCK, 256, 0, stream>>>(stag, bcur, dinv, gs, ge, ecsr);

    k_gemm0<<<N_NODES / 16, 256, 0, stream>>>(x, W0, dinv, hdA);

    k_layer<<<NGRP, 256, 0, stream>>>((const __half2*)hdA, b0, dinv, gs, ge, ecsr,
                                      Ws + 0 * 64 * 64, hs16 + (size_t)0 * N_NODES * 64, hdB);
    k_layer<<<NGRP, 256, 0, stream>>>((const __half2*)hdB, bs + 0 * 64, dinv, gs, ge, ecsr,
                                      Ws + 1 * 64 * 64, hs16 + (size_t)1 * N_NODES * 64, hdA);
    k_layer<<<NGRP, 256, 0, stream>>>((const __half2*)hdA, bs + 1 * 64, dinv, gs, ge, ecsr,
                                      Ws + 2 * 64 * 64, hs16 + (size_t)2 * N_NODES * 64, hdB);
    k_last <<<NGRP, 256, 0, stream>>>((const __half2*)hdB, bs + 2 * 64, dinv, gs, ge, ecsr,
                                      hs16, Wout, bout, out);
}

// Round 14
// 188.237 us; speedup vs baseline: 7.6454x; 7.6454x over previous
//
#include <hip/hip_runtime.h>
#include <hip/hip_fp16.h>

#define N_NODES 50000
#define N_HID   64
#define N_LAYER 4
#define N_CLASS 40
#define N_EDGES 800000

#define BSHIFT 8
#define BSIZE  256                                      // nodes per bucket
#define NBUCK  ((N_NODES + BSIZE - 1) / BSIZE)          // 196
#define BPAD   16                                       // bucket-cursor stride (64B)
#define EPT    16                                       // edges per thread (bucket pass)
#define BKCHUNK (256 * EPT)                             // 4096 edges per block
#define NBBLK  ((N_EDGES + BKCHUNK - 1) / BKCHUNK)      // 196

#define SCAP  5120                                      // fixed stag window per bucket
#define PBK   (SCAP + 15 * BSIZE)                       // 8960: padded (x16) CSR window
#define DUMMY N_NODES                                   // index of zeroed hd row

// ---------------- init: bucket cursors + dummy hd rows ----------------

__global__ void k_zerob(int* __restrict__ bcur, __half* __restrict__ hdA,
                        __half* __restrict__ hdB) {
    int t = threadIdx.x;
    if (t < NBUCK) bcur[t * BPAD] = t * SCAP;
    if (t < 64) {
        hdA[(size_t)N_NODES * 64 + t] = __float2half(0.f);
        hdB[(size_t)N_NODES * 64 + t] = __float2half(0.f);
    }
}

// ---------------- block-binned append of packed (dst<<16)|src into fixed bucket windows ----------------

__global__ void k_bucket(const int* __restrict__ src, const int* __restrict__ dst,
                         int* __restrict__ bcur, unsigned int* __restrict__ stag) {
    __shared__ int lhist[NBUCK];
    __shared__ int gbase[NBUCK];
    int t = threadIdx.x;
    for (int i = t; i < NBUCK; i += 256) lhist[i] = 0;
    __syncthreads();

    int base = blockIdx.x * BKCHUNK;
    unsigned int rec[EPT];
    int br[EPT];
#pragma unroll
    for (int i = 0; i < EPT; i++) {
        int e = base + i * 256 + t;      // coalesced
        if (e < N_EDGES) {
            int d = dst[e], s = src[e];
            int b = d >> BSHIFT;
            int r = atomicAdd(&lhist[b], 1);   // in-block rank within bucket
            rec[i] = ((unsigned int)d << 16) | (unsigned int)s;
            br[i]  = (b << 16) | r;            // r < 4096
        } else {
            br[i] = -1;
        }
    }
    __syncthreads();
    for (int i = t; i < NBUCK; i += 256) {
        int c = lhist[i];
        gbase[i] = c ? atomicAdd(&bcur[i * BPAD], c) : 0;
    }
    __syncthreads();
#pragma unroll
    for (int i = 0; i < EPT; i++) {
        if (br[i] >= 0) {
            int b = br[i] >> 16, r = br[i] & 0xffff;
            stag[gbase[b] + r] = rec[i];
        }
    }
}

// ---------------- per-bucket: LDS count + scan -> CSR rows padded to x16 ----------------

__global__ void k_csr2(const unsigned int* __restrict__ stag, const int* __restrict__ bcur,
                       int* __restrict__ cnt, int* __restrict__ pcurg,
                       float* __restrict__ dinv, unsigned short* __restrict__ csr16) {
    __shared__ int lcnt[BSIZE], ltmp[BSIZE], lcur[BSIZE];
    int b = blockIdx.x, t = threadIdx.x;
    int bstart = b * SCAP;
    int bend   = bcur[b * BPAD];         // post-append cursor = bucket end
    lcnt[t] = 0;
    __syncthreads();
    for (int i = bstart + t; i < bend; i += 256)
        atomicAdd(&lcnt[(stag[i] >> 16) & (BSIZE - 1)], 1);
    __syncthreads();
    int v = lcnt[t];
    int p = (v + 15) & ~15;              // padded row size (x16)
    ltmp[t] = p;
    __syncthreads();
    for (int off = 1; off < 256; off <<= 1) {
        int u = (t >= off) ? ltmp[t - off] : 0;
        __syncthreads();
        ltmp[t] += u;
        __syncthreads();
    }
    int pstart = b * PBK + ltmp[t] - p;  // node's padded CSR row start (x16 aligned)
    lcur[t] = pstart;
    int node = (b << BSHIFT) + t;
    if (node < N_NODES) {
        cnt[node]   = v;
        pcurg[node] = pstart;
        dinv[node]  = rsqrtf((float)(v + 1));
    }
    __syncthreads();
    for (int i = bstart + t; i < bend; i += 256) {
        unsigned int rec = stag[i];
        int pos = atomicAdd(&lcur[(rec >> 16) & (BSIZE - 1)], 1);
        csr16[pos] = (unsigned short)rec;
    }
    for (int i = v; i < p; i++)          // fill pad slots with dummy zero-row
        csr16[pstart + i] = (unsigned short)DUMMY;
}

// ---------------- layer-0 GEMM (tiled, 4 acc/thread): hd = half((x@W0)*dinv) ----------------

__global__ __launch_bounds__(256) void k_gemm0(const float* __restrict__ A,
                                               const float* __restrict__ W,
                                               const float* __restrict__ dinv,
                                               __half* __restrict__ hd) {
    __shared__ float As[16][128];
    int tid = threadIdx.x;
    int j  = tid & 63;
    int nl = tid >> 6;              // 0..3
    int node0 = blockIdx.x * 16;

    const float4* srcp = (const float4*)(A + (size_t)node0 * 128);
    float4* dstp = (float4*)&As[0][0];
    for (int idx = tid; idx < 16 * 128 / 4; idx += 256) dstp[idx] = srcp[idx];
    __syncthreads();

    float acc[4] = {0.f, 0.f, 0.f, 0.f};
#pragma unroll
    for (int k = 0; k < 128; k += 4) {
        float4 a0 = *(const float4*)&As[nl * 4 + 0][k];   // wave-uniform broadcast
        float4 a1 = *(const float4*)&As[nl * 4 + 1][k];
        float4 a2 = *(const float4*)&As[nl * 4 + 2][k];
        float4 a3 = *(const float4*)&As[nl * 4 + 3][k];
        float w0 = W[(k + 0) * 64 + j];
        float w1 = W[(k + 1) * 64 + j];
        float w2 = W[(k + 2) * 64 + j];
        float w3 = W[(k + 3) * 64 + j];
        acc[0] = fmaf(a0.w, w3, fmaf(a0.z, w2, fmaf(a0.y, w1, fmaf(a0.x, w0, acc[0]))));
        acc[1] = fmaf(a1.w, w3, fmaf(a1.z, w2, fmaf(a1.y, w1, fmaf(a1.x, w0, acc[1]))));
        acc[2] = fmaf(a2.w, w3, fmaf(a2.z, w2, fmaf(a2.y, w1, fmaf(a2.x, w0, acc[2]))));
        acc[3] = fmaf(a3.w, w3, fmaf(a3.z, w2, fmaf(a3.y, w1, fmaf(a3.x, w0, acc[3]))));
    }
#pragma unroll
    for (int i = 0; i < 4; i++) {
        int n = node0 + nl * 4 + i;
        hd[(size_t)n * 64 + j] = __float2half(acc[i] * dinv[n]);
    }
}

// ---------------- agg for one node by one wave: 16 feature-slots x 4 edge-parity ----------------
// Each lane loads 8B of a row -> one wave load = 4 edge rows (512B). Indices via uint2 (4/load).
// Returns 4-feature sums (features f*4..f*4+3) reduced over all parity groups.

__device__ __forceinline__ float4 agg_node16(const uint2* __restrict__ hd2,
                                             const int* __restrict__ cnt,
                                             const int* __restrict__ pcur,
                                             const unsigned short* __restrict__ csr16,
                                             int n, int f, int par) {
    int k = pcur[n] + par * 4;
    int iters = (cnt[n] + 15) >> 4;
    float s0 = 0.f, s1 = 0.f, s2 = 0.f, s3 = 0.f;
    for (int it = 0; it < iters; ++it, k += 16) {
        uint2 idx = *(const uint2*)(csr16 + k);           // 4 edge indices (8B)
        int a0 = idx.x & 0xffff, a1 = idx.x >> 16;
        int a2 = idx.y & 0xffff, a3 = idx.y >> 16;
        uint2 r0 = hd2[(size_t)a0 * 16 + f];              // 8B = 4 halves
        uint2 r1 = hd2[(size_t)a1 * 16 + f];
        uint2 r2 = hd2[(size_t)a2 * 16 + f];
        uint2 r3 = hd2[(size_t)a3 * 16 + f];
        float2 p0 = __half22float2(*(const __half2*)&r0.x), q0 = __half22float2(*(const __half2*)&r0.y);
        float2 p1 = __half22float2(*(const __half2*)&r1.x), q1 = __half22float2(*(const __half2*)&r1.y);
        float2 p2 = __half22float2(*(const __half2*)&r2.x), q2 = __half22float2(*(const __half2*)&r2.y);
        float2 p3 = __half22float2(*(const __half2*)&r3.x), q3 = __half22float2(*(const __half2*)&r3.y);
        s0 += (p0.x + p1.x) + (p2.x + p3.x);
        s1 += (p0.y + p1.y) + (p2.y + p3.y);
        s2 += (q0.x + q1.x) + (q2.x + q3.x);
        s3 += (q0.y + q1.y) + (q2.y + q3.y);
    }
    // reduce over the 4 parity groups (lane bits 4,5)
    s0 += __shfl_xor(s0, 16, 64); s1 += __shfl_xor(s1, 16, 64);
    s2 += __shfl_xor(s2, 16, 64); s3 += __shfl_xor(s3, 16, 64);
    s0 += __shfl_xor(s0, 32, 64); s1 += __shfl_xor(s1, 32, 64);
    s2 += __shfl_xor(s2, 32, 64); s3 += __shfl_xor(s3, 32, 64);
    return make_float4(s0, s1, s2, s3);
}

// ---------------- fused: agg(layer l, wave=node) + gemm(layer l+1, wave0 4-acc) ----------------

__global__ __launch_bounds__(256) void k_fused(const uint2* __restrict__ hd2_in,
                                               const float* __restrict__ b,
                                               const float* __restrict__ dinv,
                                               const int* __restrict__ cnt,
                                               const int* __restrict__ pcur,
                                               const unsigned short* __restrict__ csr16,
                                               const float* __restrict__ W,
                                               __half* __restrict__ hs_out,
                                               __half* __restrict__ hd_out) {
    __shared__ float As[4][64];
    int tid = threadIdx.x;
    int w = tid >> 6, lane = tid & 63;
    int f = lane & 15, par = lane >> 4;
    int node0 = blockIdx.x * 4;
    int n = node0 + w;

    float4 s = agg_node16(hd2_in, cnt, pcur, csr16, n, f, par);
    if (par == 0) {
        float dv = dinv[n];
        uint2 sr = hd2_in[(size_t)n * 16 + f];            // self row (8B)
        float2 sp = __half22float2(*(const __half2*)&sr.x);
        float2 sq = __half22float2(*(const __half2*)&sr.y);
        float o0 = fmaxf(fmaf(s.x + sp.x, dv, b[f * 4 + 0]), 0.f);
        float o1 = fmaxf(fmaf(s.y + sp.y, dv, b[f * 4 + 1]), 0.f);
        float o2 = fmaxf(fmaf(s.z + sq.x, dv, b[f * 4 + 2]), 0.f);
        float o3 = fmaxf(fmaf(s.w + sq.y, dv, b[f * 4 + 3]), 0.f);
        *(float4*)&As[w][f * 4] = make_float4(o0, o1, o2, o3);
        __half2 h0 = __halves2half2(__float2half(o0), __float2half(o1));
        __half2 h1 = __halves2half2(__float2half(o2), __float2half(o3));
        uint2 pk;
        pk.x = *(const unsigned int*)&h0;
        pk.y = *(const unsigned int*)&h1;
        ((uint2*)hs_out)[(size_t)n * 16 + f] = pk;        // 8B store
    }
    __syncthreads();

    // wave 0: gemm for the block's 4 nodes, 4 acc/thread (4x W reuse, ILP 4)
    if (tid < 64) {
        float acc[4] = {0.f, 0.f, 0.f, 0.f};
#pragma unroll
        for (int k = 0; k < 64; k += 4) {
            float4 a0 = *(const float4*)&As[0][k];   // wave-uniform broadcasts
            float4 a1 = *(const float4*)&As[1][k];
            float4 a2 = *(const float4*)&As[2][k];
            float4 a3 = *(const float4*)&As[3][k];
            float w0 = W[(k + 0) * 64 + tid];
            float w1 = W[(k + 1) * 64 + tid];
            float w2 = W[(k + 2) * 64 + tid];
            float w3 = W[(k + 3) * 64 + tid];
            acc[0] = fmaf(a0.w, w3, fmaf(a0.z, w2, fmaf(a0.y, w1, fmaf(a0.x, w0, acc[0]))));
            acc[1] = fmaf(a1.w, w3, fmaf(a1.z, w2, fmaf(a1.y, w1, fmaf(a1.x, w0, acc[1]))));
            acc[2] = fmaf(a2.w, w3, fmaf(a2.z, w2, fmaf(a2.y, w1, fmaf(a2.x, w0, acc[2]))));
            acc[3] = fmaf(a3.w, w3, fmaf(a3.z, w2, fmaf(a3.y, w1, fmaf(a3.x, w0, acc[3]))));
        }
#pragma unroll
        for (int i = 0; i < 4; i++) {
            int nn = node0 + i;
            hd_out[(size_t)nn * 64 + tid] = __float2half(acc[i] * dinv[nn]);
        }
    }
}

// ---------------- last: agg(l3) + attention + projection(wave0 4-acc) ----------------

__global__ __launch_bounds__(256) void k_last(const uint2* __restrict__ hd2_in,
                                              const float* __restrict__ b,
                                              const float* __restrict__ dinv,
                                              const int* __restrict__ cnt,
                                              const int* __restrict__ pcur,
                                              const unsigned short* __restrict__ csr16,
                                              const __half* __restrict__ hs16,
                                              const float* __restrict__ Wout,
                                              const float* __restrict__ bout,
                                              float* __restrict__ out) {
    __shared__ float As[4][64];
    int tid = threadIdx.x;
    int w = tid >> 6, lane = tid & 63;
    int f = lane & 15, par = lane >> 4;
    int node0 = blockIdx.x * 4;
    int n = node0 + w;

    float4 s = agg_node16(hd2_in, cnt, pcur, csr16, n, f, par);
    if (par == 0) {
        float dv = dinv[n];
        uint2 sr = hd2_in[(size_t)n * 16 + f];
        float2 sp = __half22float2(*(const __half2*)&sr.x);
        float2 sq = __half22float2(*(const __half2*)&sr.y);
        float o0 = fmaxf(fmaf(s.x + sp.x, dv, b[f * 4 + 0]), 0.f);
        float o1 = fmaxf(fmaf(s.y + sp.y, dv, b[f * 4 + 1]), 0.f);
        float o2 = fmaxf(fmaf(s.z + sq.x, dv, b[f * 4 + 2]), 0.f);
        float o3 = fmaxf(fmaf(s.w + sq.y, dv, b[f * 4 + 3]), 0.f);
        *(float4*)&As[w][f * 4] = make_float4(o0, o1, o2, o3);
    }
    __builtin_amdgcn_wave_barrier();

    // attention over layers (wave = node; feature = lane)
    float v[N_LAYER], sc[N_LAYER];
#pragma unroll
    for (int l = 0; l < 3; l++) {
        float val = __half2float(hs16[((size_t)l * N_NODES + n) * 64 + lane]);
        v[l]  = val;
        sc[l] = val * val;
    }
    v[3]  = As[w][lane];
    sc[3] = v[3] * v[3];
#pragma unroll
    for (int off = 32; off > 0; off >>= 1) {
#pragma unroll
        for (int l = 0; l < N_LAYER; l++) sc[l] += __shfl_xor(sc[l], off, 64);
    }
    float m = fmaxf(fmaxf(sc[0], sc[1]), fmaxf(sc[2], sc[3]));
    float e[N_LAYER];
    float sum = 0.f;
#pragma unroll
    for (int l = 0; l < N_LAYER; l++) { e[l] = __expf(sc[l] - m); sum += e[l]; }
    float inv = 1.f / sum;
    float bl = 0.f;
#pragma unroll
    for (int l = 0; l < N_LAYER; l++) bl = fmaf(e[l] * inv, v[l], bl);
    As[w][lane] = bl;                     // own-thread address: ordered after read
    __syncthreads();

    // wave 0: projection for the block's 4 nodes, 4 acc/thread
    if (tid < 64 && tid < N_CLASS) {
        float acc[4] = {bout[tid], bout[tid], bout[tid], bout[tid]};
#pragma unroll
        for (int k = 0; k < 64; k += 4) {
            float4 a0 = *(const float4*)&As[0][k];
            float4 a1 = *(const float4*)&As[1][k];
            float4 a2 = *(const float4*)&As[2][k];
            float4 a3 = *(const float4*)&As[3][k];
            float w0 = Wout[(k + 0) * N_CLASS + tid];
            float w1 = Wout[(k + 1) * N_CLASS + tid];
            float w2 = Wout[(k + 2) * N_CLASS + tid];
            float w3 = Wout[(k + 3) * N_CLASS + tid];
            acc[0] = fmaf(a0.w, w3, fmaf(a0.z, w2, fmaf(a0.y, w1, fmaf(a0.x, w0, acc[0]))));
            acc[1] = fmaf(a1.w, w3, fmaf(a1.z, w2, fmaf(a1.y, w1, fmaf(a1.x, w0, acc[1]))));
            acc[2] = fmaf(a2.w, w3, fmaf(a2.z, w2, fmaf(a2.y, w1, fmaf(a2.x, w0, acc[2]))));
            acc[3] = fmaf(a3.w, w3, fmaf(a3.z, w2, fmaf(a3.y, w1, fmaf(a3.x, w0, acc[3]))));
        }
#pragma unroll
        for (int i = 0; i < 4; i++)
            out[(size_t)(node0 + i) * N_CLASS + tid] = acc[i];
    }
}

// ---------------- launch ----------------

extern "C" void kernel_launch(void* const* d_in, const int* in_sizes, int n_in,
                              void* d_out, int out_size, void* d_ws, size_t ws_size,
                              hipStream_t stream) {
    const float* x    = (const float*)d_in[0];
    const float* W0   = (const float*)d_in[1];
    const float* b0   = (const float*)d_in[2];
    const float* Ws   = (const float*)d_in[3];
    const float* bs   = (const float*)d_in[4];
    const float* Wout = (const float*)d_in[5];
    const float* bout = (const float*)d_in[6];
    const int*   ei   = (const int*)d_in[7];
    const int* src = ei;
    const int* dst = ei + N_EDGES;
    float* out = (float*)d_out;

    int*            cnt   = (int*)d_ws;                             // N
    int*            pcur  = cnt + N_NODES;                          // N
    int*            bcur  = pcur + N_NODES;                         // NBUCK*BPAD
    float*          dinv  = (float*)(bcur + NBUCK * BPAD);          // N
    unsigned short* csr16 = (unsigned short*)(dinv + N_NODES);      // NBUCK*PBK (x16-pad)
    __half*         hdA   = (__half*)(csr16 + (size_t)NBUCK * PBK); // (N+1)*64
    __half*         hdB   = hdA + (size_t)(N_NODES + 1) * 64;       // (N+1)*64
    __half*         hs16  = hdB + (size_t)(N_NODES + 1) * 64;       // 3*N*64
    unsigned int*   stag  = (unsigned int*)hs16;                    // NBUCK*SCAP, aliased (build only)

    k_zerob <<<1, 256, 0, stream>>>(bcur, hdA, hdB);
    k_bucket<<<NBBLK, 256, 0, stream>>>(src, dst, bcur, stag);
    k_csr2  <<<NBUCK, 256, 0, stream>>>(stag, bcur, cnt, pcur, dinv, csr16);

    k_gemm0<<<N_NODES / 16, 256, 0, stream>>>(x, W0, dinv, hdA);

    const int NB = N_NODES / 4;   // 12500 blocks x 256 threads, wave = node (agg)

    k_fused<<<NB, 256, 0, stream>>>((const uint2*)hdA, b0, dinv, cnt, pcur, csr16,
                                    Ws + 0 * 64 * 64, hs16 + (size_t)0 * N_NODES * 64, hdB);
    k_fused<<<NB, 256, 0, stream>>>((const uint2*)hdB, bs + 0 * 64, dinv, cnt, pcur, csr16,
                                    Ws + 1 * 64 * 64, hs16 + (size_t)1 * N_NODES * 64, hdA);
    k_fused<<<NB, 256, 0, stream>>>((const uint2*)hdA, bs + 1 * 64, dinv, cnt, pcur, csr16,
                                    Ws + 2 * 64 * 64, hs16 + (size_t)2 * N_NODES * 64, hdB);
    k_last <<<NB, 256, 0, stream>>>((const uint2*)hdB, bs + 2 * 64, dinv, cnt, pcur, csr16,
                                    hs16, Wout, bout, out);
}